// Round 7
// baseline (442.928 us; speedup 1.0000x reference)
//
#include <hip/hip_runtime.h>
#include <math.h>

#define TOPK 10
#define G 8              // stage-1 blocks per batch
#define CHUNK 1050       // N / G
#define NT 256
#define S1_PER 5         // ceil(CHUNK / NT)
#define FILLB 2048       // fill-only blocks

// ---------- helpers ----------

// Order-preserving f32 -> u32 (monotone: a<b  =>  enc(a)<enc(b)).
__device__ __forceinline__ unsigned int f32_ordkey(float f) {
    unsigned int u = __float_as_uint(f);
    return (u & 0x80000000u) ? ~u : (u | 0x80000000u);
}

__device__ __forceinline__ unsigned long long wave_max_u64(unsigned long long k) {
    #pragma unroll
    for (int off = 32; off > 0; off >>= 1) {
        unsigned long long o = __shfl_xor(k, off, 64);
        k = (o > k) ? o : k;
    }
    return k;
}

__device__ __forceinline__ unsigned long long wave_min_u64(unsigned long long k) {
    #pragma unroll
    for (int off = 32; off > 0; off >>= 1) {
        unsigned long long o = __shfl_xor(k, off, 64);
        k = (o < k) ? o : k;
    }
    return k;
}

__device__ __forceinline__ float iou_box(float4 bx, float g0, float g1, float g2,
                                         float g3, float area_g) {
    const float ix1 = fmaxf(bx.x, g0), iy1 = fmaxf(bx.y, g1);
    const float ix2 = fminf(bx.z, g2), iy2 = fminf(bx.w, g3);
    const float inter  = fmaxf(ix2 - ix1, 0.0f) * fmaxf(iy2 - iy1, 0.0f);
    const float area_p = (bx.z - bx.x) * (bx.w - bx.y);
    return fmaxf(inter / (area_p + area_g - inter), 1e-9f);
}

// ---------- single fused kernel ----------
// grid = BG + FILLB blocks x 256.
//   blocks [0, BG):        stage-1 for (b,g): per-wave top-10 keys + any(is_in)
//                          + min-d2 key into d_ws. Lazy gather: boxes/scores
//                          only for in-box anchors (~3%).
//   blocks [BG, BG+FILLB): grid-stride float4 zero-fill of d_out.
// All blocks then: __threadfence (release) + atomicAdd(counter). The LAST
// block (acquire fence) merges 320 candidates/batch -> top-10 -> scatters.
// Ordering guarantees the scatter lands after every zero-fill store.
__global__ __launch_bounds__(NT) void taa_all(
    const float* __restrict__ scores,   // B,N,C
    const float* __restrict__ boxes,    // B,N,4
    const float* __restrict__ anchors,  // N,2
    const int*   __restrict__ labels,   // B
    const float* __restrict__ gts,      // B,1,4
    float4* __restrict__ out4, size_t n4,
    unsigned long long* __restrict__ cand,  // [B][320]
    unsigned long long* __restrict__ dkw,   // [B][32]
    int* __restrict__ anyf,                 // [B][32]
    unsigned int* __restrict__ counter,     // pre-zeroed each call
    float* __restrict__ tb, float* __restrict__ ts, float* __restrict__ fg,
    int BG, int B, int N, int C)
{
    const int tid  = threadIdx.x;
    const int lane = tid & 63;
    const int wave = tid >> 6;          // 0..3

    if (blockIdx.x < (unsigned)BG) {
        // ----- stage 1 -----
        const int b    = blockIdx.x / G;
        const int g    = blockIdx.x % G;
        const int base = g * CHUNK;

        const float g0 = gts[b*4+0], g1 = gts[b*4+1], g2 = gts[b*4+2], g3 = gts[b*4+3];
        const int   cls = labels[b];
        const float gcx = (g0 + g2) * 0.5f, gcy = (g1 + g3) * 0.5f;
        const float area_g = (g2 - g0) * (g3 - g1);

        unsigned long long key[S1_PER];
        unsigned long long dkey = ~0ull;
        int anyin = 0;

        #pragma unroll
        for (int j = 0; j < S1_PER; ++j) {
            const int ii = tid + j * NT;
            const int i  = base + ii;
            if (ii < CHUNK) {
                const float2 a = ((const float2*)anchors)[i];
                const bool in = (a.x >= g0) && (a.x <= g2) && (a.y >= g1) && (a.y <= g3);
                anyin |= (int)in;

                const float dx = a.x - gcx, dy = a.y - gcy;
                const float d2 = dx*dx + dy*dy;
                const unsigned long long dk =
                    ((unsigned long long)__float_as_uint(d2) << 32) | (unsigned int)i;
                dkey = dk < dkey ? dk : dkey;   // ties -> lower idx (low bits)

                float m = -1.0f;
                if (in) {   // lazy: boxes/scores touched only for in-box anchors
                    const float4 bx = ((const float4*)boxes)[(size_t)b * N + i];
                    const float iou = iou_box(bx, g0, g1, g2, g3, area_g);
                    const float sc = scores[((size_t)b * N + i) * C + cls];
                    const float cs = 1.0f / (1.0f + expf(-sc));
                    const float i2 = iou * iou;
                    m = sqrtf(cs) * (i2 * i2 * i2);
                }
                key[j] = ((unsigned long long)f32_ordkey(m) << 32) | (unsigned int)(~(unsigned int)i);
            } else {
                key[j] = 0ull;          // below any real key (key(-1.0) > 0)
            }
        }

        // Wave top-10 by iterative max + zero-out (keys unique: idx in low bits).
        unsigned long long* wc = cand + ((size_t)b * (G*4*TOPK)) + (g*4 + wave) * TOPK;
        for (int r = 0; r < TOPK; ++r) {
            unsigned long long lm = key[0];
            #pragma unroll
            for (int j = 1; j < S1_PER; ++j) lm = key[j] > lm ? key[j] : lm;
            const unsigned long long w = wave_max_u64(lm);
            #pragma unroll
            for (int j = 0; j < S1_PER; ++j) if (key[j] == w) key[j] = 0ull;
            if (lane == 0) wc[r] = w;
        }

        const int wany = __any(anyin);
        const unsigned long long wdk = wave_min_u64(dkey);
        if (lane == 0) {
            anyf[b * (G*4) + g*4 + wave] = wany;
            dkw [b * (G*4) + g*4 + wave] = wdk;
        }
    } else {
        // ----- zero-fill -----
        const size_t fb     = blockIdx.x - (unsigned)BG;
        const size_t stride = (size_t)FILLB * NT;
        const float4 z = make_float4(0.f, 0.f, 0.f, 0.f);
        for (size_t i = fb * NT + tid; i < n4; i += stride)
            out4[i] = z;
    }

    // ----- arrival: release + count; last block merges -----
    __threadfence();                     // release my cand/dkw/anyf or zero stores
    __shared__ int s_last;
    if (tid == 0)
        s_last = (atomicAdd(counter, 1u) == (unsigned)(gridDim.x - 1));
    __syncthreads();
    if (!s_last) return;

    __threadfence();                     // acquire everyone's writes

    // ----- merge + scatter: 4 waves x 16 batches -----
    for (int b = wave; b < B; b += 4) {
        const float g0 = gts[b*4+0], g1 = gts[b*4+1], g2 = gts[b*4+2], g3 = gts[b*4+3];
        const bool  gt_valid = (g2 > g0) && (g3 > g1);
        const int   cls = labels[b];
        const float area_g = (g2 - g0) * (g3 - g1);

        const int a = __any((lane < 32) ? anyf[b*32 + lane] : 0);

        int wi = -1;    // winner anchor index for this lane (if any)
        if (a) {
            unsigned long long k[5];
            #pragma unroll
            for (int j = 0; j < 5; ++j) k[j] = cand[(size_t)b * 320 + j*64 + lane];

            unsigned long long mywin = 0ull;
            for (int r = 0; r < TOPK; ++r) {
                unsigned long long lm = k[0];
                #pragma unroll
                for (int j = 1; j < 5; ++j) lm = k[j] > lm ? k[j] : lm;
                const unsigned long long w = wave_max_u64(lm);
                #pragma unroll
                for (int j = 0; j < 5; ++j) if (k[j] == w) k[j] = 0ull;
                if (lane == r) mywin = w;
            }
            // sel <=> metric >= +0.0 <=> top bit set (only in-box anchors qualify).
            if (lane < TOPK && (mywin & 0x8000000000000000ull))
                wi = (int)(~(unsigned int)(mywin & 0xffffffffu));
        } else {
            // Fallback: single winner = global argmin-d2 (metric > 0 always).
            unsigned long long dk = (lane < 32) ? dkw[b*32 + lane] : ~0ull;
            const unsigned long long m = wave_min_u64(dk);
            if (lane == 0) wi = (int)(m & 0xffffffffu);
        }

        if (gt_valid && wi >= 0) {
            const float4 bx = ((const float4*)boxes)[(size_t)b * N + wi];
            const float iou = iou_box(bx, g0, g1, g2, g3, area_g);
            fg[(size_t)b * N + wi] = 1.0f;
            ((float4*)tb)[(size_t)b * N + wi] = make_float4(g0, g1, g2, g3);
            ts[((size_t)b * N + wi) * C + cls] = iou;
        }
    }
}

extern "C" void kernel_launch(void* const* d_in, const int* in_sizes, int n_in,
                              void* d_out, int out_size, void* d_ws, size_t ws_size,
                              hipStream_t stream) {
    const float* scores  = (const float*)d_in[0];
    const float* boxes   = (const float*)d_in[1];
    const float* anchors = (const float*)d_in[2];
    const int*   labels  = (const int*)d_in[3];
    const float* gts     = (const float*)d_in[4];

    const int B = in_sizes[3];
    const int N = in_sizes[2] / 2;
    const int C = in_sizes[0] / (B * N);
    const int BG = B * G;

    float* tb = (float*)d_out;
    float* ts = tb + (size_t)B * N * 4;
    float* fg = ts + (size_t)B * N * C;

    // Workspace layout (8B-aligned).
    unsigned long long* cand = (unsigned long long*)d_ws;                 // B*320*8
    unsigned long long* dkw  = cand + (size_t)B * 320;                    // B*32*8
    int*                anyf = (int*)(dkw + (size_t)B * 32);              // B*32*4
    unsigned int*       ctr  = (unsigned int*)(anyf + (size_t)B * 32);    // 8 B

    const size_t n4 = ((size_t)out_size * sizeof(float)) / sizeof(float4);

    // d_ws is poisoned, not zeroed — reset the arrival counter each call.
    hipMemsetAsync(ctr, 0, 8, stream);

    taa_all<<<BG + FILLB, NT, 0, stream>>>(scores, boxes, anchors, labels, gts,
                                           (float4*)d_out, n4, cand, dkw, anyf,
                                           ctr, tb, ts, fg, BG, B, N, C);
}

// Round 9
// 48.181 us; speedup vs baseline: 9.1930x; 9.1930x over previous
//
#include <hip/hip_runtime.h>
#include <math.h>

#define TOPK 10
#define G 8              // stage-1 blocks per batch
#define CHUNK 1050       // N / G
#define NT 256
#define S1_PER 5         // ceil(CHUNK / NT)
#define FILLB 2048       // fill-only blocks

typedef float f32x4 __attribute__((ext_vector_type(4)));  // native vec type for NT stores

// ---------- helpers ----------

// Order-preserving f32 -> u32 (monotone: a<b  =>  enc(a)<enc(b)).
__device__ __forceinline__ unsigned int f32_ordkey(float f) {
    unsigned int u = __float_as_uint(f);
    return (u & 0x80000000u) ? ~u : (u | 0x80000000u);
}

__device__ __forceinline__ unsigned long long wave_max_u64(unsigned long long k) {
    #pragma unroll
    for (int off = 32; off > 0; off >>= 1) {
        unsigned long long o = __shfl_xor(k, off, 64);
        k = (o > k) ? o : k;
    }
    return k;
}

__device__ __forceinline__ unsigned long long wave_min_u64(unsigned long long k) {
    #pragma unroll
    for (int off = 32; off > 0; off >>= 1) {
        unsigned long long o = __shfl_xor(k, off, 64);
        k = (o < k) ? o : k;
    }
    return k;
}

__device__ __forceinline__ float iou_box(float4 bx, float g0, float g1, float g2,
                                         float g3, float area_g) {
    const float ix1 = fmaxf(bx.x, g0), iy1 = fmaxf(bx.y, g1);
    const float ix2 = fminf(bx.z, g2), iy2 = fminf(bx.w, g3);
    const float inter  = fmaxf(ix2 - ix1, 0.0f) * fmaxf(iy2 - iy1, 0.0f);
    const float area_p = (bx.z - bx.x) * (bx.w - bx.y);
    return fmaxf(inter / (area_p + area_g - inter), 1e-9f);
}

// ---------- fused kernel: role-split, NO cross-block sync ----------
// grid = BG + FILLB blocks x 256.
//   blocks [0, BG):        stage-1 ONLY for (b,g).
//   blocks [BG, BG+FILLB): zero-fill ONLY — NON-TEMPORAL stores (bypass L2:
//                          avoid dirtying 32MB of L2 that the dependent-
//                          dispatch boundary must write back, and avoid the
//                          L2 eviction chain in steady state).
// Cross-block ordering (stage1 results -> merge, zeros -> scatter) is handled
// by the K1->K2 dispatch boundary: ONE L2 writeback instead of per-block
// fences (R7: per-block __threadfence cost ~170ns serialized each -> 443us).
__global__ __launch_bounds__(NT) void taa_fused(
    const float* __restrict__ scores,   // B,N,C
    const float* __restrict__ boxes,    // B,N,4
    const float* __restrict__ anchors,  // N,2
    const int*   __restrict__ labels,   // B
    const float* __restrict__ gts,      // B,1,4
    f32x4* __restrict__ out4, size_t n4,
    unsigned long long* __restrict__ cand,  // [B][320]
    unsigned long long* __restrict__ dkw,   // [B][32]
    int* __restrict__ anyf,                 // [B][32]
    int BG, int N, int C)
{
    const int tid = threadIdx.x;

    if (blockIdx.x < (unsigned)BG) {
        const int b    = blockIdx.x / G;
        const int g    = blockIdx.x % G;
        const int lane = tid & 63;
        const int wave = tid >> 6;      // 0..3
        const int base = g * CHUNK;

        const float g0 = gts[b*4+0], g1 = gts[b*4+1], g2 = gts[b*4+2], g3 = gts[b*4+3];
        const int   cls = labels[b];
        const float gcx = (g0 + g2) * 0.5f, gcy = (g1 + g3) * 0.5f;
        const float area_g = (g2 - g0) * (g3 - g1);

        unsigned long long key[S1_PER];
        unsigned long long dkey = ~0ull;
        int anyin = 0;

        #pragma unroll
        for (int j = 0; j < S1_PER; ++j) {
            const int ii = tid + j * NT;
            const int i  = base + ii;
            if (ii < CHUNK) {
                const float2 a = ((const float2*)anchors)[i];
                const bool in = (a.x >= g0) && (a.x <= g2) && (a.y >= g1) && (a.y <= g3);
                anyin |= (int)in;

                const float dx = a.x - gcx, dy = a.y - gcy;
                const float d2 = dx*dx + dy*dy;
                const unsigned long long dk =
                    ((unsigned long long)__float_as_uint(d2) << 32) | (unsigned int)i;
                dkey = dk < dkey ? dk : dkey;   // ties -> lower idx (low bits)

                float m = -1.0f;
                if (in) {   // lazy: boxes/scores touched only for in-box anchors (~3%)
                    const float4 bx = ((const float4*)boxes)[(size_t)b * N + i];
                    const float iou = iou_box(bx, g0, g1, g2, g3, area_g);
                    const float sc = scores[((size_t)b * N + i) * C + cls];
                    const float cs = 1.0f / (1.0f + expf(-sc));
                    const float i2 = iou * iou;
                    m = sqrtf(cs) * (i2 * i2 * i2);
                }
                key[j] = ((unsigned long long)f32_ordkey(m) << 32) | (unsigned int)(~(unsigned int)i);
            } else {
                key[j] = 0ull;          // below any real key (key(-1.0) > 0)
            }
        }

        // Wave top-10 by iterative max + zero-out (keys unique: idx in low bits).
        unsigned long long* wc = cand + ((size_t)b * (G*4*TOPK)) + (g*4 + wave) * TOPK;
        for (int r = 0; r < TOPK; ++r) {
            unsigned long long lm = key[0];
            #pragma unroll
            for (int j = 1; j < S1_PER; ++j) lm = key[j] > lm ? key[j] : lm;
            const unsigned long long w = wave_max_u64(lm);
            #pragma unroll
            for (int j = 0; j < S1_PER; ++j) if (key[j] == w) key[j] = 0ull;
            if (lane == 0) wc[r] = w;
        }

        // Wave any(is_in) + min-d2 key.
        const int wany = __any(anyin);
        const unsigned long long wdk = wave_min_u64(dkey);
        if (lane == 0) {
            anyf[b * (G*4) + g*4 + wave] = wany;
            dkw [b * (G*4) + g*4 + wave] = wdk;
        }
        return;   // stage-1 blocks take no fill share
    }

    // Fill-only blocks: non-temporal zero stores.
    const size_t fb     = blockIdx.x - (unsigned)BG;
    const size_t stride = (size_t)FILLB * NT;
    const f32x4 z = (f32x4)(0.0f);
    for (size_t i = fb * NT + tid; i < n4; i += stride)
        __builtin_nontemporal_store(z, &out4[i]);
}

// ---------- stage 2: merge + scatter ----------
// grid = B blocks x 64 threads.
__global__ __launch_bounds__(64) void taa_stage2(
    const float* __restrict__ boxes,    // B,N,4
    const int*   __restrict__ labels,   // B
    const float* __restrict__ gts,      // B,1,4
    const unsigned long long* __restrict__ cand,
    const unsigned long long* __restrict__ dkw,
    const int* __restrict__ anyf,
    float* __restrict__ tb, float* __restrict__ ts, float* __restrict__ fg,
    int N, int C)
{
    const int b    = blockIdx.x;
    const int lane = threadIdx.x;

    const float g0 = gts[b*4+0], g1 = gts[b*4+1], g2 = gts[b*4+2], g3 = gts[b*4+3];
    const bool  gt_valid = (g2 > g0) && (g3 > g1);
    const int   cls = labels[b];
    const float area_g = (g2 - g0) * (g3 - g1);

    const int a = __any((lane < 32) ? anyf[b*32 + lane] : 0);

    int wi = -1;          // winner anchor index for this lane (if any)
    if (a) {
        unsigned long long k[5];
        #pragma unroll
        for (int j = 0; j < 5; ++j) k[j] = cand[(size_t)b * 320 + j*64 + lane];

        unsigned long long mywin = 0ull;
        for (int r = 0; r < TOPK; ++r) {
            unsigned long long lm = k[0];
            #pragma unroll
            for (int j = 1; j < 5; ++j) lm = k[j] > lm ? k[j] : lm;
            const unsigned long long w = wave_max_u64(lm);
            #pragma unroll
            for (int j = 0; j < 5; ++j) if (k[j] == w) k[j] = 0ull;
            if (lane == r) mywin = w;
        }
        // sel <=> metric >= +0.0 <=> top bit set (only in-box anchors qualify).
        if (lane < TOPK && (mywin & 0x8000000000000000ull))
            wi = (int)(~(unsigned int)(mywin & 0xffffffffu));
    } else {
        // Fallback: single winner = global argmin-d2 (metric > 0 always).
        unsigned long long dk = (lane < 32) ? dkw[b*32 + lane] : ~0ull;
        const unsigned long long m = wave_min_u64(dk);
        if (lane == 0) wi = (int)(m & 0xffffffffu);
    }

    if (gt_valid && wi >= 0) {
        const float4 bx = ((const float4*)boxes)[(size_t)b * N + wi];
        const float iou = iou_box(bx, g0, g1, g2, g3, area_g);
        fg[(size_t)b * N + wi] = 1.0f;
        ((float4*)tb)[(size_t)b * N + wi] = make_float4(g0, g1, g2, g3);
        ts[((size_t)b * N + wi) * C + cls] = iou;
    }
}

extern "C" void kernel_launch(void* const* d_in, const int* in_sizes, int n_in,
                              void* d_out, int out_size, void* d_ws, size_t ws_size,
                              hipStream_t stream) {
    const float* scores  = (const float*)d_in[0];
    const float* boxes   = (const float*)d_in[1];
    const float* anchors = (const float*)d_in[2];
    const int*   labels  = (const int*)d_in[3];
    const float* gts     = (const float*)d_in[4];

    const int B = in_sizes[3];
    const int N = in_sizes[2] / 2;
    const int C = in_sizes[0] / (B * N);
    const int BG = B * G;

    float* tb = (float*)d_out;
    float* ts = tb + (size_t)B * N * 4;
    float* fg = ts + (size_t)B * N * C;

    // Workspace layout (8B-aligned).
    unsigned long long* cand = (unsigned long long*)d_ws;                 // B*320*8
    unsigned long long* dkw  = cand + (size_t)B * 320;                    // B*32*8
    int*                anyf = (int*)(dkw + (size_t)B * 32);              // B*32*4

    const size_t n4 = ((size_t)out_size * sizeof(float)) / sizeof(f32x4);

    taa_fused<<<BG + FILLB, NT, 0, stream>>>(scores, boxes, anchors, labels, gts,
                                             (f32x4*)d_out, n4, cand, dkw, anyf,
                                             BG, N, C);

    taa_stage2<<<B, 64, 0, stream>>>(boxes, labels, gts, cand, dkw, anyf,
                                     tb, ts, fg, N, C);
}

// Round 10
// 36.545 us; speedup vs baseline: 12.1201x; 1.3184x over previous
//
#include <hip/hip_runtime.h>
#include <math.h>

#define TOPK 10
#define G 8              // stage-1 blocks per batch
#define CHUNK 1050       // N / G
#define NT 256
#define S1_PER 5         // ceil(CHUNK / NT)
#define FILLB 1536       // fill-only blocks; 512 stage1 + 1536 fill = 2048
                         // = exactly max co-residency (8 blocks/CU x 256 CU)
                         // so NO block starts late with a full fill share.

// ---------- helpers ----------

// Order-preserving f32 -> u32 (monotone: a<b  =>  enc(a)<enc(b)).
__device__ __forceinline__ unsigned int f32_ordkey(float f) {
    unsigned int u = __float_as_uint(f);
    return (u & 0x80000000u) ? ~u : (u | 0x80000000u);
}

__device__ __forceinline__ unsigned long long wave_max_u64(unsigned long long k) {
    #pragma unroll
    for (int off = 32; off > 0; off >>= 1) {
        unsigned long long o = __shfl_xor(k, off, 64);
        k = (o > k) ? o : k;
    }
    return k;
}

__device__ __forceinline__ unsigned long long wave_min_u64(unsigned long long k) {
    #pragma unroll
    for (int off = 32; off > 0; off >>= 1) {
        unsigned long long o = __shfl_xor(k, off, 64);
        k = (o < k) ? o : k;
    }
    return k;
}

__device__ __forceinline__ float iou_box(float4 bx, float g0, float g1, float g2,
                                         float g3, float area_g) {
    const float ix1 = fmaxf(bx.x, g0), iy1 = fmaxf(bx.y, g1);
    const float ix2 = fminf(bx.z, g2), iy2 = fminf(bx.w, g3);
    const float inter  = fmaxf(ix2 - ix1, 0.0f) * fmaxf(iy2 - iy1, 0.0f);
    const float area_p = (bx.z - bx.x) * (bx.w - bx.y);
    return fmaxf(inter / (area_p + area_g - inter), 1e-9f);
}

// ---------- fused kernel: role-split, grid sized to exact co-residency ----------
// grid = 512 + FILLB = 2048 blocks x 256.
//   blocks [0, 512):      stage-1 ONLY for (b,g) — exit early (~8us), hidden
//                         under the fill.
//   blocks [512, 2048):   zero-fill ONLY (plain cached stores — R9 showed
//                         non-temporal stores run at ~4.6 TB/s vs ~6+ cached).
// Cross-block ordering (stage1 results -> merge, zeros -> scatter) is handled
// by the K1->K2 dispatch boundary (R7: per-block __threadfence = disaster).
__global__ __launch_bounds__(NT) void taa_fused(
    const float* __restrict__ scores,   // B,N,C
    const float* __restrict__ boxes,    // B,N,4
    const float* __restrict__ anchors,  // N,2
    const int*   __restrict__ labels,   // B
    const float* __restrict__ gts,      // B,1,4
    float4* __restrict__ out4, size_t n4,
    unsigned long long* __restrict__ cand,  // [B][320]
    unsigned long long* __restrict__ dkw,   // [B][32]
    int* __restrict__ anyf,                 // [B][32]
    int BG, int N, int C)
{
    const int tid = threadIdx.x;

    if (blockIdx.x < (unsigned)BG) {
        const int b    = blockIdx.x / G;
        const int g    = blockIdx.x % G;
        const int lane = tid & 63;
        const int wave = tid >> 6;      // 0..3
        const int base = g * CHUNK;

        const float g0 = gts[b*4+0], g1 = gts[b*4+1], g2 = gts[b*4+2], g3 = gts[b*4+3];
        const int   cls = labels[b];
        const float gcx = (g0 + g2) * 0.5f, gcy = (g1 + g3) * 0.5f;
        const float area_g = (g2 - g0) * (g3 - g1);

        unsigned long long key[S1_PER];
        unsigned long long dkey = ~0ull;
        int anyin = 0;

        #pragma unroll
        for (int j = 0; j < S1_PER; ++j) {
            const int ii = tid + j * NT;
            const int i  = base + ii;
            if (ii < CHUNK) {
                const float2 a = ((const float2*)anchors)[i];
                const bool in = (a.x >= g0) && (a.x <= g2) && (a.y >= g1) && (a.y <= g3);
                anyin |= (int)in;

                const float dx = a.x - gcx, dy = a.y - gcy;
                const float d2 = dx*dx + dy*dy;
                const unsigned long long dk =
                    ((unsigned long long)__float_as_uint(d2) << 32) | (unsigned int)i;
                dkey = dk < dkey ? dk : dkey;   // ties -> lower idx (low bits)

                float m = -1.0f;
                if (in) {   // lazy: boxes/scores touched only for in-box anchors (~3%)
                    const float4 bx = ((const float4*)boxes)[(size_t)b * N + i];
                    const float iou = iou_box(bx, g0, g1, g2, g3, area_g);
                    const float sc = scores[((size_t)b * N + i) * C + cls];
                    const float cs = 1.0f / (1.0f + expf(-sc));
                    const float i2 = iou * iou;
                    m = sqrtf(cs) * (i2 * i2 * i2);
                }
                key[j] = ((unsigned long long)f32_ordkey(m) << 32) | (unsigned int)(~(unsigned int)i);
            } else {
                key[j] = 0ull;          // below any real key (key(-1.0) > 0)
            }
        }

        // Wave top-10 by iterative max + zero-out (keys unique: idx in low bits).
        unsigned long long* wc = cand + ((size_t)b * (G*4*TOPK)) + (g*4 + wave) * TOPK;
        for (int r = 0; r < TOPK; ++r) {
            unsigned long long lm = key[0];
            #pragma unroll
            for (int j = 1; j < S1_PER; ++j) lm = key[j] > lm ? key[j] : lm;
            const unsigned long long w = wave_max_u64(lm);
            #pragma unroll
            for (int j = 0; j < S1_PER; ++j) if (key[j] == w) key[j] = 0ull;
            if (lane == 0) wc[r] = w;
        }

        // Wave any(is_in) + min-d2 key.
        const int wany = __any(anyin);
        const unsigned long long wdk = wave_min_u64(dkey);
        if (lane == 0) {
            anyf[b * (G*4) + g*4 + wave] = wany;
            dkw [b * (G*4) + g*4 + wave] = wdk;
        }
        return;   // stage-1 blocks take no fill share
    }

    // Fill-only blocks: plain cached float4 stores.
    const size_t fb     = blockIdx.x - (unsigned)BG;
    const size_t stride = (size_t)FILLB * NT;
    const float4 z = make_float4(0.f, 0.f, 0.f, 0.f);
    for (size_t i = fb * NT + tid; i < n4; i += stride)
        out4[i] = z;
}

// ---------- stage 2: merge + scatter ----------
// grid = B blocks x 64 threads.
__global__ __launch_bounds__(64) void taa_stage2(
    const float* __restrict__ boxes,    // B,N,4
    const int*   __restrict__ labels,   // B
    const float* __restrict__ gts,      // B,1,4
    const unsigned long long* __restrict__ cand,
    const unsigned long long* __restrict__ dkw,
    const int* __restrict__ anyf,
    float* __restrict__ tb, float* __restrict__ ts, float* __restrict__ fg,
    int N, int C)
{
    const int b    = blockIdx.x;
    const int lane = threadIdx.x;

    const float g0 = gts[b*4+0], g1 = gts[b*4+1], g2 = gts[b*4+2], g3 = gts[b*4+3];
    const bool  gt_valid = (g2 > g0) && (g3 > g1);
    const int   cls = labels[b];
    const float area_g = (g2 - g0) * (g3 - g1);

    const int a = __any((lane < 32) ? anyf[b*32 + lane] : 0);

    int wi = -1;          // winner anchor index for this lane (if any)
    if (a) {
        unsigned long long k[5];
        #pragma unroll
        for (int j = 0; j < 5; ++j) k[j] = cand[(size_t)b * 320 + j*64 + lane];

        unsigned long long mywin = 0ull;
        for (int r = 0; r < TOPK; ++r) {
            unsigned long long lm = k[0];
            #pragma unroll
            for (int j = 1; j < 5; ++j) lm = k[j] > lm ? k[j] : lm;
            const unsigned long long w = wave_max_u64(lm);
            #pragma unroll
            for (int j = 0; j < 5; ++j) if (k[j] == w) k[j] = 0ull;
            if (lane == r) mywin = w;
        }
        // sel <=> metric >= +0.0 <=> top bit set (only in-box anchors qualify).
        if (lane < TOPK && (mywin & 0x8000000000000000ull))
            wi = (int)(~(unsigned int)(mywin & 0xffffffffu));
    } else {
        // Fallback: single winner = global argmin-d2 (metric > 0 always).
        unsigned long long dk = (lane < 32) ? dkw[b*32 + lane] : ~0ull;
        const unsigned long long m = wave_min_u64(dk);
        if (lane == 0) wi = (int)(m & 0xffffffffu);
    }

    if (gt_valid && wi >= 0) {
        const float4 bx = ((const float4*)boxes)[(size_t)b * N + wi];
        const float iou = iou_box(bx, g0, g1, g2, g3, area_g);
        fg[(size_t)b * N + wi] = 1.0f;
        ((float4*)tb)[(size_t)b * N + wi] = make_float4(g0, g1, g2, g3);
        ts[((size_t)b * N + wi) * C + cls] = iou;
    }
}

extern "C" void kernel_launch(void* const* d_in, const int* in_sizes, int n_in,
                              void* d_out, int out_size, void* d_ws, size_t ws_size,
                              hipStream_t stream) {
    const float* scores  = (const float*)d_in[0];
    const float* boxes   = (const float*)d_in[1];
    const float* anchors = (const float*)d_in[2];
    const int*   labels  = (const int*)d_in[3];
    const float* gts     = (const float*)d_in[4];

    const int B = in_sizes[3];
    const int N = in_sizes[2] / 2;
    const int C = in_sizes[0] / (B * N);
    const int BG = B * G;

    float* tb = (float*)d_out;
    float* ts = tb + (size_t)B * N * 4;
    float* fg = ts + (size_t)B * N * C;

    // Workspace layout (8B-aligned).
    unsigned long long* cand = (unsigned long long*)d_ws;                 // B*320*8
    unsigned long long* dkw  = cand + (size_t)B * 320;                    // B*32*8
    int*                anyf = (int*)(dkw + (size_t)B * 32);              // B*32*4

    const size_t n4 = ((size_t)out_size * sizeof(float)) / sizeof(float4);

    taa_fused<<<BG + FILLB, NT, 0, stream>>>(scores, boxes, anchors, labels, gts,
                                             (float4*)d_out, n4, cand, dkw, anyf,
                                             BG, N, C);

    taa_stage2<<<B, 64, 0, stream>>>(boxes, labels, gts, cand, dkw, anyf,
                                     tb, ts, fg, N, C);
}

// Round 11
// 35.546 us; speedup vs baseline: 12.4608x; 1.0281x over previous
//
#include <hip/hip_runtime.h>
#include <math.h>

#define TOPK 10
#define G 8              // stage-1 blocks per batch
#define CHUNK 1050       // N / G
#define NT 256
#define S1_PER 5         // ceil(CHUNK / NT)
#define FILLB 1536       // fill-only blocks; 512 stage1 + 1536 fill = 2048
                         // = exactly max co-residency (8 blocks/CU x 256 CU)

// ---------- helpers ----------

// Order-preserving f32 -> u32 (monotone: a<b  =>  enc(a)<enc(b)).
__device__ __forceinline__ unsigned int f32_ordkey(float f) {
    unsigned int u = __float_as_uint(f);
    return (u & 0x80000000u) ? ~u : (u | 0x80000000u);
}

__device__ __forceinline__ unsigned long long wave_max_u64(unsigned long long k) {
    #pragma unroll
    for (int off = 32; off > 0; off >>= 1) {
        unsigned long long o = __shfl_xor(k, off, 64);
        k = (o > k) ? o : k;
    }
    return k;
}

__device__ __forceinline__ unsigned long long wave_min_u64(unsigned long long k) {
    #pragma unroll
    for (int off = 32; off > 0; off >>= 1) {
        unsigned long long o = __shfl_xor(k, off, 64);
        k = (o < k) ? o : k;
    }
    return k;
}

__device__ __forceinline__ float iou_box(float4 bx, float g0, float g1, float g2,
                                         float g3, float area_g) {
    const float ix1 = fmaxf(bx.x, g0), iy1 = fmaxf(bx.y, g1);
    const float ix2 = fminf(bx.z, g2), iy2 = fminf(bx.w, g3);
    const float inter  = fmaxf(ix2 - ix1, 0.0f) * fmaxf(iy2 - iy1, 0.0f);
    const float area_p = (bx.z - bx.x) * (bx.w - bx.y);
    return fmaxf(inter / (area_p + area_g - inter), 1e-9f);
}

// ---------- fused kernel: role-split with PROPORTIONAL fill shares ----------
// grid = 512 + FILLB = 2048 blocks x 256 (exact co-residency).
//   blocks [0, 512):      stage-1 for (b,g) (~8us), THEN fill region [splitA,n4)
//                         (a ~0.69 share — sized so all blocks finish together).
//   blocks [512, 2048):   fill region [0, splitA) only.
// All 2048 resident blocks write during steady state -> max store issue rate.
// Cross-block ordering handled by the K1->K2 dispatch boundary (R7: per-block
// __threadfence = 443us disaster; R9: nontemporal stores = 4.6 TB/s regression).
__global__ __launch_bounds__(NT) void taa_fused(
    const float* __restrict__ scores,   // B,N,C
    const float* __restrict__ boxes,    // B,N,4
    const float* __restrict__ anchors,  // N,2
    const int*   __restrict__ labels,   // B
    const float* __restrict__ gts,      // B,1,4
    float4* __restrict__ out4, size_t n4, size_t splitA,
    unsigned long long* __restrict__ cand,  // [B][320]
    unsigned long long* __restrict__ dkw,   // [B][32]
    int* __restrict__ anyf,                 // [B][32]
    int BG, int N, int C)
{
    const int tid = threadIdx.x;

    if (blockIdx.x < (unsigned)BG) {
        const int b    = blockIdx.x / G;
        const int g    = blockIdx.x % G;
        const int lane = tid & 63;
        const int wave = tid >> 6;      // 0..3
        const int base = g * CHUNK;

        const float g0 = gts[b*4+0], g1 = gts[b*4+1], g2 = gts[b*4+2], g3 = gts[b*4+3];
        const int   cls = labels[b];
        const float gcx = (g0 + g2) * 0.5f, gcy = (g1 + g3) * 0.5f;
        const float area_g = (g2 - g0) * (g3 - g1);

        unsigned long long key[S1_PER];
        unsigned long long dkey = ~0ull;
        int anyin = 0;

        #pragma unroll
        for (int j = 0; j < S1_PER; ++j) {
            const int ii = tid + j * NT;
            const int i  = base + ii;
            if (ii < CHUNK) {
                const float2 a = ((const float2*)anchors)[i];
                const bool in = (a.x >= g0) && (a.x <= g2) && (a.y >= g1) && (a.y <= g3);
                anyin |= (int)in;

                const float dx = a.x - gcx, dy = a.y - gcy;
                const float d2 = dx*dx + dy*dy;
                const unsigned long long dk =
                    ((unsigned long long)__float_as_uint(d2) << 32) | (unsigned int)i;
                dkey = dk < dkey ? dk : dkey;   // ties -> lower idx (low bits)

                float m = -1.0f;
                if (in) {   // lazy: boxes/scores touched only for in-box anchors (~3%)
                    const float4 bx = ((const float4*)boxes)[(size_t)b * N + i];
                    const float iou = iou_box(bx, g0, g1, g2, g3, area_g);
                    const float sc = scores[((size_t)b * N + i) * C + cls];
                    const float cs = 1.0f / (1.0f + expf(-sc));
                    const float i2 = iou * iou;
                    m = sqrtf(cs) * (i2 * i2 * i2);
                }
                key[j] = ((unsigned long long)f32_ordkey(m) << 32) | (unsigned int)(~(unsigned int)i);
            } else {
                key[j] = 0ull;          // below any real key (key(-1.0) > 0)
            }
        }

        // Wave top-10 by iterative max + zero-out (keys unique: idx in low bits).
        unsigned long long* wc = cand + ((size_t)b * (G*4*TOPK)) + (g*4 + wave) * TOPK;
        for (int r = 0; r < TOPK; ++r) {
            unsigned long long lm = key[0];
            #pragma unroll
            for (int j = 1; j < S1_PER; ++j) lm = key[j] > lm ? key[j] : lm;
            const unsigned long long w = wave_max_u64(lm);
            #pragma unroll
            for (int j = 0; j < S1_PER; ++j) if (key[j] == w) key[j] = 0ull;
            if (lane == 0) wc[r] = w;
        }

        // Wave any(is_in) + min-d2 key.
        const int wany = __any(anyin);
        const unsigned long long wdk = wave_min_u64(dkey);
        if (lane == 0) {
            anyf[b * (G*4) + g*4 + wave] = wany;
            dkw [b * (G*4) + g*4 + wave] = wdk;
        }

        // Reduced fill share: region [splitA, n4), strided across the 512
        // stage-1 blocks. (No barrier needed before filling: fill region is
        // disjoint from everything stage-1 touches.)
        const size_t stride = (size_t)BG * NT;
        const float4 z = make_float4(0.f, 0.f, 0.f, 0.f);
        for (size_t i = splitA + (size_t)blockIdx.x * NT + tid; i < n4; i += stride)
            out4[i] = z;
        return;
    }

    // Fill-only blocks: region [0, splitA).
    const size_t fb     = blockIdx.x - (unsigned)BG;
    const size_t stride = (size_t)FILLB * NT;
    const float4 z = make_float4(0.f, 0.f, 0.f, 0.f);
    for (size_t i = fb * NT + tid; i < splitA; i += stride)
        out4[i] = z;
}

// ---------- stage 2: merge + scatter ----------
// grid = B blocks x 64 threads.
__global__ __launch_bounds__(64) void taa_stage2(
    const float* __restrict__ boxes,    // B,N,4
    const int*   __restrict__ labels,   // B
    const float* __restrict__ gts,      // B,1,4
    const unsigned long long* __restrict__ cand,
    const unsigned long long* __restrict__ dkw,
    const int* __restrict__ anyf,
    float* __restrict__ tb, float* __restrict__ ts, float* __restrict__ fg,
    int N, int C)
{
    const int b    = blockIdx.x;
    const int lane = threadIdx.x;

    const float g0 = gts[b*4+0], g1 = gts[b*4+1], g2 = gts[b*4+2], g3 = gts[b*4+3];
    const bool  gt_valid = (g2 > g0) && (g3 > g1);
    const int   cls = labels[b];
    const float area_g = (g2 - g0) * (g3 - g1);

    const int a = __any((lane < 32) ? anyf[b*32 + lane] : 0);

    int wi = -1;          // winner anchor index for this lane (if any)
    if (a) {
        unsigned long long k[5];
        #pragma unroll
        for (int j = 0; j < 5; ++j) k[j] = cand[(size_t)b * 320 + j*64 + lane];

        unsigned long long mywin = 0ull;
        for (int r = 0; r < TOPK; ++r) {
            unsigned long long lm = k[0];
            #pragma unroll
            for (int j = 1; j < 5; ++j) lm = k[j] > lm ? k[j] : lm;
            const unsigned long long w = wave_max_u64(lm);
            #pragma unroll
            for (int j = 0; j < 5; ++j) if (k[j] == w) k[j] = 0ull;
            if (lane == r) mywin = w;
        }
        // sel <=> metric >= +0.0 <=> top bit set (only in-box anchors qualify).
        if (lane < TOPK && (mywin & 0x8000000000000000ull))
            wi = (int)(~(unsigned int)(mywin & 0xffffffffu));
    } else {
        // Fallback: single winner = global argmin-d2 (metric > 0 always).
        unsigned long long dk = (lane < 32) ? dkw[b*32 + lane] : ~0ull;
        const unsigned long long m = wave_min_u64(dk);
        if (lane == 0) wi = (int)(m & 0xffffffffu);
    }

    if (gt_valid && wi >= 0) {
        const float4 bx = ((const float4*)boxes)[(size_t)b * N + wi];
        const float iou = iou_box(bx, g0, g1, g2, g3, area_g);
        fg[(size_t)b * N + wi] = 1.0f;
        ((float4*)tb)[(size_t)b * N + wi] = make_float4(g0, g1, g2, g3);
        ts[((size_t)b * N + wi) * C + cls] = iou;
    }
}

extern "C" void kernel_launch(void* const* d_in, const int* in_sizes, int n_in,
                              void* d_out, int out_size, void* d_ws, size_t ws_size,
                              hipStream_t stream) {
    const float* scores  = (const float*)d_in[0];
    const float* boxes   = (const float*)d_in[1];
    const float* anchors = (const float*)d_in[2];
    const int*   labels  = (const int*)d_in[3];
    const float* gts     = (const float*)d_in[4];

    const int B = in_sizes[3];
    const int N = in_sizes[2] / 2;
    const int C = in_sizes[0] / (B * N);
    const int BG = B * G;

    float* tb = (float*)d_out;
    float* ts = tb + (size_t)B * N * 4;
    float* fg = ts + (size_t)B * N * C;

    // Workspace layout (8B-aligned).
    unsigned long long* cand = (unsigned long long*)d_ws;                 // B*320*8
    unsigned long long* dkw  = cand + (size_t)B * 320;                    // B*32*8
    int*                anyf = (int*)(dkw + (size_t)B * 32);              // B*32*4

    const size_t n4 = ((size_t)out_size * sizeof(float)) / sizeof(float4);

    // Proportional split: stage1 blocks get ~11/16 of a fill share each
    // (they spend ~8us of a ~26us kernel on stage-1 first).
    // weights: 1536 fill x 1.0 + 512 stage1 x 11/16 -> denom = 1536 + 352 = 1888.
    const size_t splitA = (n4 * 1536u) / 1888u;

    taa_fused<<<BG + FILLB, NT, 0, stream>>>(scores, boxes, anchors, labels, gts,
                                             (float4*)d_out, n4, splitA,
                                             cand, dkw, anyf, BG, N, C);

    taa_stage2<<<B, 64, 0, stream>>>(boxes, labels, gts, cand, dkw, anyf,
                                     tb, ts, fg, N, C);
}

// Round 12
// 35.372 us; speedup vs baseline: 12.5222x; 1.0049x over previous
//
#include <hip/hip_runtime.h>
#include <math.h>

#define TOPK 10
#define G 8              // stage-1 blocks per batch
#define CHUNK 1050       // N / G  (even)
#define NT 256
#define S1_V4 3          // float4 anchor loads/thread: 3 x 2 anchors = 6 >= 1050/256*2
#define S1_K 6           // keys per thread (2 per float4 load)
#define FILLB 1536       // fill-only blocks; 512 stage1 + 1536 fill = 2048
                         // = exactly max co-residency (8 blocks/CU x 256 CU)

// ---------- helpers ----------

// Order-preserving f32 -> u32 (monotone: a<b  =>  enc(a)<enc(b)).
__device__ __forceinline__ unsigned int f32_ordkey(float f) {
    unsigned int u = __float_as_uint(f);
    return (u & 0x80000000u) ? ~u : (u | 0x80000000u);
}

__device__ __forceinline__ unsigned long long wave_max_u64(unsigned long long k) {
    #pragma unroll
    for (int off = 32; off > 0; off >>= 1) {
        unsigned long long o = __shfl_xor(k, off, 64);
        k = (o > k) ? o : k;
    }
    return k;
}

__device__ __forceinline__ unsigned long long wave_min_u64(unsigned long long k) {
    #pragma unroll
    for (int off = 32; off > 0; off >>= 1) {
        unsigned long long o = __shfl_xor(k, off, 64);
        k = (o < k) ? o : k;
    }
    return k;
}

__device__ __forceinline__ float iou_box(float4 bx, float g0, float g1, float g2,
                                         float g3, float area_g) {
    const float ix1 = fmaxf(bx.x, g0), iy1 = fmaxf(bx.y, g1);
    const float ix2 = fminf(bx.z, g2), iy2 = fminf(bx.w, g3);
    const float inter  = fmaxf(ix2 - ix1, 0.0f) * fmaxf(iy2 - iy1, 0.0f);
    const float area_p = (bx.z - bx.x) * (bx.w - bx.y);
    return fmaxf(inter / (area_p + area_g - inter), 1e-9f);
}

// ---------- fused kernel: role-split with proportional fill shares ----------
// grid = 512 + FILLB = 2048 blocks x 256 (exact co-residency).
//   blocks [0, 512):      stage-1 for (b,g) (~4.5us, float4 anchor loads,
//                         lazy box/score gather), THEN fill [splitA, n4)
//                         (~0.83 share so all blocks finish together).
//   blocks [512, 2048):   fill [0, splitA) only.
// Cross-block ordering handled by the K1->K2 dispatch boundary (R7: per-block
// __threadfence = 443us disaster; R9: nontemporal stores = 4.6 TB/s regression).
__global__ __launch_bounds__(NT) void taa_fused(
    const float* __restrict__ scores,   // B,N,C
    const float* __restrict__ boxes,    // B,N,4
    const float* __restrict__ anchors,  // N,2
    const int*   __restrict__ labels,   // B
    const float* __restrict__ gts,      // B,1,4
    float4* __restrict__ out4, size_t n4, size_t splitA,
    unsigned long long* __restrict__ cand,  // [B][320]
    unsigned long long* __restrict__ dkw,   // [B][32]
    int* __restrict__ anyf,                 // [B][32]
    int BG, int N, int C)
{
    const int tid = threadIdx.x;

    if (blockIdx.x < (unsigned)BG) {
        const int b     = blockIdx.x / G;
        const int g     = blockIdx.x % G;
        const int lane  = tid & 63;
        const int wave  = tid >> 6;     // 0..3
        const int base  = g * CHUNK;
        const int base2 = g * (CHUNK / 2);  // float4 index into anchors

        const float g0 = gts[b*4+0], g1 = gts[b*4+1], g2 = gts[b*4+2], g3 = gts[b*4+3];
        const int   cls = labels[b];
        const float gcx = (g0 + g2) * 0.5f, gcy = (g1 + g3) * 0.5f;
        const float area_g = (g2 - g0) * (g3 - g1);

        const float4* __restrict__ anch4 = (const float4*)anchors;  // elem k = anchors[2k..2k+1]

        unsigned long long key[S1_K];
        unsigned long long dkey = ~0ull;
        int anyin = 0;

        #pragma unroll
        for (int j = 0; j < S1_V4; ++j) {
            const int q   = tid + j * NT;   // float4 index within chunk
            const int ii0 = 2 * q;          // anchor offset within chunk
            if (ii0 < CHUNK) {              // CHUNK even -> ii0+1 < CHUNK too
                const float4 av = anch4[base2 + q];
                #pragma unroll
                for (int h = 0; h < 2; ++h) {
                    const float ax = h ? av.z : av.x;
                    const float ay = h ? av.w : av.y;
                    const int   i  = base + ii0 + h;

                    const bool in = (ax >= g0) && (ax <= g2) && (ay >= g1) && (ay <= g3);
                    anyin |= (int)in;

                    const float dx = ax - gcx, dy = ay - gcy;
                    const float d2 = dx*dx + dy*dy;
                    const unsigned long long dk =
                        ((unsigned long long)__float_as_uint(d2) << 32) | (unsigned int)i;
                    dkey = dk < dkey ? dk : dkey;   // ties -> lower idx (low bits)

                    float m = -1.0f;
                    if (in) {   // lazy: boxes/scores only for in-box anchors (~3%)
                        const float4 bx = ((const float4*)boxes)[(size_t)b * N + i];
                        const float iou = iou_box(bx, g0, g1, g2, g3, area_g);
                        const float sc = scores[((size_t)b * N + i) * C + cls];
                        const float cs = 1.0f / (1.0f + expf(-sc));
                        const float i2 = iou * iou;
                        m = sqrtf(cs) * (i2 * i2 * i2);
                    }
                    key[2*j+h] = ((unsigned long long)f32_ordkey(m) << 32)
                               | (unsigned int)(~(unsigned int)i);
                }
            } else {
                key[2*j]   = 0ull;      // below any real key (key(-1.0) > 0)
                key[2*j+1] = 0ull;
            }
        }

        // Wave top-10 by iterative max + zero-out (keys unique: idx in low bits).
        unsigned long long* wc = cand + ((size_t)b * (G*4*TOPK)) + (g*4 + wave) * TOPK;
        for (int r = 0; r < TOPK; ++r) {
            unsigned long long lm = key[0];
            #pragma unroll
            for (int j = 1; j < S1_K; ++j) lm = key[j] > lm ? key[j] : lm;
            const unsigned long long w = wave_max_u64(lm);
            #pragma unroll
            for (int j = 0; j < S1_K; ++j) if (key[j] == w) key[j] = 0ull;
            if (lane == 0) wc[r] = w;
        }

        // Wave any(is_in) + min-d2 key.
        const int wany = __any(anyin);
        const unsigned long long wdk = wave_min_u64(dkey);
        if (lane == 0) {
            anyf[b * (G*4) + g*4 + wave] = wany;
            dkw [b * (G*4) + g*4 + wave] = wdk;
        }

        // Reduced fill share: [splitA, n4), strided across the 512 stage-1 blocks.
        const size_t stride = (size_t)BG * NT;
        const float4 z = make_float4(0.f, 0.f, 0.f, 0.f);
        for (size_t i = splitA + (size_t)blockIdx.x * NT + tid; i < n4; i += stride)
            out4[i] = z;
        return;
    }

    // Fill-only blocks: region [0, splitA).
    const size_t fb     = blockIdx.x - (unsigned)BG;
    const size_t stride = (size_t)FILLB * NT;
    const float4 z = make_float4(0.f, 0.f, 0.f, 0.f);
    for (size_t i = fb * NT + tid; i < splitA; i += stride)
        out4[i] = z;
}

// ---------- stage 2: merge + scatter ----------
// grid = B blocks x 64 threads.
__global__ __launch_bounds__(64) void taa_stage2(
    const float* __restrict__ boxes,    // B,N,4
    const int*   __restrict__ labels,   // B
    const float* __restrict__ gts,      // B,1,4
    const unsigned long long* __restrict__ cand,
    const unsigned long long* __restrict__ dkw,
    const int* __restrict__ anyf,
    float* __restrict__ tb, float* __restrict__ ts, float* __restrict__ fg,
    int N, int C)
{
    const int b    = blockIdx.x;
    const int lane = threadIdx.x;

    const float g0 = gts[b*4+0], g1 = gts[b*4+1], g2 = gts[b*4+2], g3 = gts[b*4+3];
    const bool  gt_valid = (g2 > g0) && (g3 > g1);
    const int   cls = labels[b];
    const float area_g = (g2 - g0) * (g3 - g1);

    const int a = __any((lane < 32) ? anyf[b*32 + lane] : 0);

    int wi = -1;          // winner anchor index for this lane (if any)
    if (a) {
        unsigned long long k[5];
        #pragma unroll
        for (int j = 0; j < 5; ++j) k[j] = cand[(size_t)b * 320 + j*64 + lane];

        unsigned long long mywin = 0ull;
        for (int r = 0; r < TOPK; ++r) {
            unsigned long long lm = k[0];
            #pragma unroll
            for (int j = 1; j < 5; ++j) lm = k[j] > lm ? k[j] : lm;
            const unsigned long long w = wave_max_u64(lm);
            #pragma unroll
            for (int j = 0; j < 5; ++j) if (k[j] == w) k[j] = 0ull;
            if (lane == r) mywin = w;
        }
        // sel <=> metric >= +0.0 <=> top bit set (only in-box anchors qualify).
        if (lane < TOPK && (mywin & 0x8000000000000000ull))
            wi = (int)(~(unsigned int)(mywin & 0xffffffffu));
    } else {
        // Fallback: single winner = global argmin-d2 (metric > 0 always).
        unsigned long long dk = (lane < 32) ? dkw[b*32 + lane] : ~0ull;
        const unsigned long long m = wave_min_u64(dk);
        if (lane == 0) wi = (int)(m & 0xffffffffu);
    }

    if (gt_valid && wi >= 0) {
        const float4 bx = ((const float4*)boxes)[(size_t)b * N + wi];
        const float iou = iou_box(bx, g0, g1, g2, g3, area_g);
        fg[(size_t)b * N + wi] = 1.0f;
        ((float4*)tb)[(size_t)b * N + wi] = make_float4(g0, g1, g2, g3);
        ts[((size_t)b * N + wi) * C + cls] = iou;
    }
}

extern "C" void kernel_launch(void* const* d_in, const int* in_sizes, int n_in,
                              void* d_out, int out_size, void* d_ws, size_t ws_size,
                              hipStream_t stream) {
    const float* scores  = (const float*)d_in[0];
    const float* boxes   = (const float*)d_in[1];
    const float* anchors = (const float*)d_in[2];
    const int*   labels  = (const int*)d_in[3];
    const float* gts     = (const float*)d_in[4];

    const int B = in_sizes[3];
    const int N = in_sizes[2] / 2;
    const int C = in_sizes[0] / (B * N);
    const int BG = B * G;

    float* tb = (float*)d_out;
    float* ts = tb + (size_t)B * N * 4;
    float* fg = ts + (size_t)B * N * C;

    // Workspace layout (8B-aligned).
    unsigned long long* cand = (unsigned long long*)d_ws;                 // B*320*8
    unsigned long long* dkw  = cand + (size_t)B * 320;                    // B*32*8
    int*                anyf = (int*)(dkw + (size_t)B * 32);              // B*32*4

    const size_t n4 = ((size_t)out_size * sizeof(float)) / sizeof(float4);

    // Proportional split: stage1 blocks spend ~4.5us of a ~26.5us kernel on
    // stage-1 -> fill share ~0.83. weights: 1536 + 512*0.83 = 1961.
    const size_t splitA = (n4 * 1536u) / 1961u;

    taa_fused<<<BG + FILLB, NT, 0, stream>>>(scores, boxes, anchors, labels, gts,
                                             (float4*)d_out, n4, splitA,
                                             cand, dkw, anyf, BG, N, C);

    taa_stage2<<<B, 64, 0, stream>>>(boxes, labels, gts, cand, dkw, anyf,
                                     tb, ts, fg, N, C);
}